// Round 9
// baseline (183.584 us; speedup 1.0000x reference)
//
#include <hip/hip_runtime.h>
#include <math.h>

#define B_   128
#define T_   50
#define MI_  32
#define E_   128
#define EW_  16
#define D_   144
#define G_   432        // 3*D
#define N_   (B_*T_)    // 6400

// ---------------------------------------------------------------------------
// K1: basket embedding v2 — parallel gather (r3 config, known good).
// ---------------------------------------------------------------------------
__global__ __launch_bounds__(256) void embed_kernel(
    const int* __restrict__ x,            // [N_][33]
    const float* __restrict__ encode_w,   // [100000][128]  (row 0 == 0)
    const float* __restrict__ wchange_w,  // [2][16]
    float* __restrict__ seq)              // [N_][144]
{
    int n = blockIdx.x;
    int tid = threadIdx.x;
    int i = tid >> 3;        // item 0..31
    int j = tid & 7;         // col chunk [16j, 16j+16)

    __shared__ int xi[33];
    __shared__ __align__(16) float part[32 * 132];  // stride 132 words
    __shared__ float cntf[32];

    if (tid < 33) xi[tid] = x[n * 33 + tid];
    __syncthreads();

    int it = xi[i];
    const float* row = &encode_w[(size_t)it * E_];
    float4 v0 = *(const float4*)&row[16 * j + 0];
    float4 v1 = *(const float4*)&row[16 * j + 4];
    float4 v2 = *(const float4*)&row[16 * j + 8];
    float4 v3 = *(const float4*)&row[16 * j + 12];

    float* p = &part[i * 132 + 16 * j];
    *(float4*)&p[0]  = v0;
    *(float4*)&p[4]  = v1;
    *(float4*)&p[8]  = v2;
    *(float4*)&p[12] = v3;
    if (j == 0) cntf[i] = (it != 0) ? 1.f : 0.f;
    __syncthreads();

    if (tid < E_) {
        int c = tid;
        float s = 0.f, cn = 0.f;
        #pragma unroll
        for (int k = 0; k < 32; ++k) {
            s  += part[k * 132 + c];   // 2-way bank aliasing: free
            cn += cntf[k];             // broadcast: free
        }
        seq[n * D_ + c] = s / fmaxf(cn, 1.f);
    } else if (tid < E_ + EW_) {
        int c = tid - E_;
        seq[n * D_ + E_ + c] = wchange_w[xi[32] * EW_ + c];
    }
}

// ---------------------------------------------------------------------------
// K2/K4: single-buffer 64x64 tiled GEMM (best measured config).
// ---------------------------------------------------------------------------
#define GK   144
#define GBK  48
#define GPAD 68

__global__ __launch_bounds__(256) void gemm_bias_kernel(
    const float* __restrict__ A,
    const float* __restrict__ Bw,
    const float* __restrict__ bias,
    float* __restrict__ C,
    int M, int N)
{
    __shared__ float As[GBK * GPAD];
    __shared__ float Bs[GBK * GPAD];

    int tid = threadIdx.x;
    int row0 = blockIdx.x * 64;
    int col0 = blockIdx.y * 64;
    int tx = tid & 15;        // col group
    int ty = tid >> 4;        // row group

    float acc[4][4] = {};

    int sr = tid >> 2;
    int skq0 = tid & 3;

    for (int k0 = 0; k0 < GK; k0 += GBK) {
        __syncthreads();
        #pragma unroll
        for (int i = 0; i < 3; ++i) {
            int kq = skq0 + i * 4;          // 0..11  (48 k / 4)
            float4 a = *(const float4*)&A[(size_t)(row0 + sr) * GK + k0 + kq * 4];
            int nrow = col0 + sr;
            float4 b = make_float4(0.f, 0.f, 0.f, 0.f);
            if (nrow < N)
                b = *(const float4*)&Bw[(size_t)nrow * GK + k0 + kq * 4];
            As[(kq * 4 + 0) * GPAD + sr] = a.x;
            As[(kq * 4 + 1) * GPAD + sr] = a.y;
            As[(kq * 4 + 2) * GPAD + sr] = a.z;
            As[(kq * 4 + 3) * GPAD + sr] = a.w;
            Bs[(kq * 4 + 0) * GPAD + sr] = b.x;
            Bs[(kq * 4 + 1) * GPAD + sr] = b.y;
            Bs[(kq * 4 + 2) * GPAD + sr] = b.z;
            Bs[(kq * 4 + 3) * GPAD + sr] = b.w;
        }
        __syncthreads();

        #pragma unroll 4
        for (int k = 0; k < GBK; ++k) {
            float4 a4 = *(const float4*)&As[k * GPAD + ty * 4];
            float4 b4 = *(const float4*)&Bs[k * GPAD + tx * 4];
            float av[4] = {a4.x, a4.y, a4.z, a4.w};
            float bv[4] = {b4.x, b4.y, b4.z, b4.w};
            #pragma unroll
            for (int i = 0; i < 4; ++i)
                #pragma unroll
                for (int j = 0; j < 4; ++j)
                    acc[i][j] = fmaf(av[i], bv[j], acc[i][j]);
        }
    }

    int c = col0 + tx * 4;
    if (c < N) {
        float4 bb = *(const float4*)&bias[c];
        #pragma unroll
        for (int i = 0; i < 4; ++i) {
            int r = row0 + ty * 4 + i;
            float4 o;
            o.x = acc[i][0] + bb.x;
            o.y = acc[i][1] + bb.y;
            o.z = acc[i][2] + bb.z;
            o.w = acc[i][3] + bb.w;
            *(float4*)&C[(size_t)r * N + c] = o;
        }
    }
}

// ---------------------------------------------------------------------------
// K3: GRU v9 = v8 (balanced 512 threads, best measured 51us) + PACKED FP32
// dot phase.  Counter re-read: VALUBusy ~29% is chip-wide; only 128/256 CUs
// hold a block -> active-CU VALUBusy ~58% => the dot phase's 130 scalar
// v_fma_f32 (260 issue-cyc/wave/step) is the dominant cost.  CDNA4's 157TF
// fp32 peak requires VOP3P v_pk_fma_f32 (2 FMA/lane/inst); the compiler
// never auto-packs.  Convert w/hv to float2 pairs + inline-asm pk_fma:
// 130 fma -> 65 pk_fma + 7 horizontal adds (~45% dot-issue reduction).
// Numerics: each 20-k chunk becomes even-k + odd-k partial sums — benign
// reorder (the chunked+butterfly order already differs from reference).
// Everything else (DPP butterfly, gh path, dense elementwise, 2 barriers)
// is v8 verbatim.
// ---------------------------------------------------------------------------
typedef float v2f __attribute__((ext_vector_type(2)));

__device__ __forceinline__ v2f pk_fma(v2f a, v2f b, v2f c) {
    v2f d;
    asm("v_pk_fma_f32 %0, %1, %2, %3" : "=v"(d) : "v"(a), "v"(b), "v"(c));
    return d;
}

template<int CTRL>
__device__ __forceinline__ float dpp_xor_add(float x) {
    int y = __builtin_amdgcn_mov_dpp(__float_as_int(x), CTRL, 0xF, 0xF, true);
    return x + __int_as_float(y);
}
#define DPP_RED3(v) \
    v = dpp_xor_add<0xB1>(v); v = dpp_xor_add<0x4E>(v); v = dpp_xor_add<0x141>(v);

__global__ __launch_bounds__(512, 2) void gru_kernel(
    const float* __restrict__ gi,     // [N_][432]
    const float* __restrict__ w_hh,   // [432][144]
    const float* __restrict__ b_hh,   // [432]
    const float* __restrict__ h0,     // [128][144]
    float* __restrict__ hseq,         // [N_][144]
    float* __restrict__ hlast)        // [128][144]
{
    int b = blockIdx.x;
    int tid = threadIdx.x;
    int g = tid >> 3;       // 0..63
    int s = tid & 7;        // k-chunk [20s, 20s+20)
    int k0 = s * 20;

    // row block: first 48 groups take 7 rows, last 16 take 6 (48*7+16*6=432)
    bool g7 = (g < 48);                       // wave-uniform
    int rb = g7 ? 7 * g : 336 + 6 * (g - 48); // base row
    int rc = g7 ? 7 : 6;                      // row count

    __shared__ __align__(16) float h[160];   // k-padded; [144..159] stay 0
    __shared__ float gh[G_];

    // weights into VGPR pairs (zero-padded past k=143; unused 7th row = 0)
    v2f w[7][10];
    #pragma unroll
    for (int r = 0; r < 7; ++r) {
        #pragma unroll
        for (int q = 0; q < 5; ++q) {
            int k = k0 + 4 * q;
            float4 t = make_float4(0.f, 0.f, 0.f, 0.f);
            if (r < rc && k < D_)
                t = *(const float4*)&w_hh[(size_t)(rb + r) * D_ + k];
            w[r][2 * q + 0] = (v2f){t.x, t.y};
            w[r][2 * q + 1] = (v2f){t.z, t.w};
        }
    }
    float bias = (s < rc) ? b_hh[rb + s] : 0.f;

    if (tid < 160) h[tid] = (tid < D_) ? h0[b * D_ + tid] : 0.f;
    __syncthreads();

    // gi pipeline: registers hold step t's values at top of iteration t
    float gir = 0.f, giz = 0.f, gin = 0.f;
    if (tid < D_) {
        const float* gp = &gi[(size_t)(b * T_) * G_];
        gir = gp[tid];
        giz = gp[D_ + tid];
        gin = gp[2 * D_ + tid];
    }

    for (int t = 0; t < T_; ++t) {
        int n = b * T_ + t;

        float girU = gir, gizU = giz, ginU = gin;
        if (tid < D_ && t + 1 < T_) {
            const float* gp = &gi[(size_t)(n + 1) * G_];
            gir = gp[tid];
            giz = gp[D_ + tid];
            gin = gp[2 * D_ + tid];
        }

        // h chunk: 5 conflict-free ds_read_b128 -> 10 float2 pairs
        v2f hv[10];
        #pragma unroll
        for (int q = 0; q < 5; ++q) {
            float4 t4 = *(const float4*)&h[k0 + 4 * q];
            hv[2 * q + 0] = (v2f){t4.x, t4.y};
            hv[2 * q + 1] = (v2f){t4.z, t4.w};
        }

        // 6 (or 7) rows x 10 packed-k dots: v_pk_fma_f32, 2 FMA/inst
        v2f c0 = {0.f, 0.f}, c1 = c0, c2 = c0, c3 = c0, c4 = c0, c5 = c0;
        v2f c6 = c0;
        #pragma unroll
        for (int kk = 0; kk < 10; ++kk) {
            v2f hk = hv[kk];
            c0 = pk_fma(w[0][kk], hk, c0);
            c1 = pk_fma(w[1][kk], hk, c1);
            c2 = pk_fma(w[2][kk], hk, c2);
            c3 = pk_fma(w[3][kk], hk, c3);
            c4 = pk_fma(w[4][kk], hk, c4);
            c5 = pk_fma(w[5][kk], hk, c5);
        }
        if (g7) {
            #pragma unroll
            for (int kk = 0; kk < 10; ++kk)
                c6 = pk_fma(w[6][kk], hv[kk], c6);
        }
        float a0 = c0.x + c0.y, a1 = c1.x + c1.y, a2 = c2.x + c2.y;
        float a3 = c3.x + c3.y, a4 = c4.x + c4.y, a5 = c5.x + c5.y;
        float a6 = c6.x + c6.y;

        // reduce across the 8 k-chunk lanes: VALU DPP butterfly (no LDS)
        DPP_RED3(a0); DPP_RED3(a1); DPP_RED3(a2);
        DPP_RED3(a3); DPP_RED3(a4); DPP_RED3(a5);
        if (g7) { DPP_RED3(a6); }

        // lane s writes row rb+s (s<rc); all 8 lanes hold all sums
        float myacc = a0;
        if (s == 1) myacc = a1;
        if (s == 2) myacc = a2;
        if (s == 3) myacc = a3;
        if (s == 4) myacc = a4;
        if (s == 5) myacc = a5;
        if (s == 6) myacc = a6;
        if (s < rc) gh[rb + s] = myacc + bias;
        __syncthreads();

        if (tid < D_) {
            float r = 1.f / (1.f + __expf(-(girU + gh[tid])));
            float z = 1.f / (1.f + __expf(-(gizU + gh[D_ + tid])));
            float narg = ginU + r * gh[2 * D_ + tid];
            narg = fminf(fmaxf(narg, -15.f), 15.f);
            float e2 = __expf(-2.f * narg);
            float nn = (1.f - e2) / (1.f + e2);
            float hn = (1.f - z) * nn + z * h[tid];
            hseq[(size_t)n * D_ + tid] = hn;
            h[tid] = hn;
        }
        __syncthreads();
    }

    if (tid < D_) hlast[b * D_ + tid] = h[tid];
}

// ---------------------------------------------------------------------------
extern "C" void kernel_launch(void* const* d_in, const int* in_sizes, int n_in,
                              void* d_out, int out_size, void* d_ws, size_t ws_size,
                              hipStream_t stream)
{
    const int*   x         = (const int*)d_in[0];
    // d_in[1] = lengths (unused by the reference computation)
    const float* hidden    = (const float*)d_in[2];
    const float* encode_w  = (const float*)d_in[3];
    const float* wchange_w = (const float*)d_in[4];
    const float* w_ih      = (const float*)d_in[5];
    const float* w_hh      = (const float*)d_in[6];
    const float* b_ih      = (const float*)d_in[7];
    const float* b_hh      = (const float*)d_in[8];
    const float* fc_w      = (const float*)d_in[9];
    const float* fc_b      = (const float*)d_in[10];

    float* out = (float*)d_out;              // [N_][128] then [128][144]
    float* ws  = (float*)d_ws;
    float* seq  = ws;                        //   921600 floats
    float* gi   = ws + 921600;               //  2764800 floats
    float* hseq = ws + 921600 + 2764800;     //   921600 floats  (18.4 MB total)

    // K1: embedding (parallel gather v2)
    embed_kernel<<<N_, 256, 0, stream>>>(x, encode_w, wchange_w, seq);

    // K2: gi = seq @ w_ih^T + b_ih   (M=6400, N=432)
    gemm_bias_kernel<<<dim3(N_ / 64, (G_ + 63) / 64), 256, 0, stream>>>(
        seq, w_ih, b_ih, gi, N_, G_);

    // K3: GRU over T=50 (v9: balanced 512 threads + packed fp32 dot)
    gru_kernel<<<B_, 512, 0, stream>>>(gi, w_hh, b_hh, hidden, hseq,
                                       out + (size_t)N_ * E_);

    // K4: dynamic_user = hseq @ fc_w^T + fc_b   (M=6400, N=128)
    gemm_bias_kernel<<<dim3(N_ / 64, E_ / 64), 256, 0, stream>>>(
        hseq, fc_w, fc_b, out, N_, E_);
}